// Round 12
// baseline (123.339 us; speedup 1.0000x reference)
//
#include <hip/hip_runtime.h>
#include <math.h>

#define Bn 4
#define Tn 4096
#define En 256
#define An 64
#define PLS 72    // P/O LDS row stride in shorts (144 B, 16B-aligned)
#define WLS 264   // W LDS row stride in shorts (528 B, 16B-aligned)

typedef __attribute__((ext_vector_type(8))) short short8;
typedef __attribute__((ext_vector_type(8))) __bf16 bf16x8;
typedef __attribute__((ext_vector_type(4))) float f32x4;
typedef __attribute__((ext_vector_type(4))) short short4v;
typedef __attribute__((ext_vector_type(2))) unsigned int uint2v;

__device__ __forceinline__ f32x4 mfma16(short8 a, short8 b, f32x4 c) {
    return __builtin_amdgcn_mfma_f32_16x16x32_bf16(
        __builtin_bit_cast(bf16x8, a), __builtin_bit_cast(bf16x8, b), c, 0, 0, 0);
}
__device__ __forceinline__ unsigned short f2bf(float x) {   // native RNE cvt
    return __builtin_bit_cast(unsigned short, (__bf16)x);
}
__device__ __forceinline__ float bf2f(unsigned short h) {
    return __builtin_bit_cast(float, (unsigned int)h << 16);
}
__device__ __forceinline__ unsigned int packbf2(float lo, float hi) {
    return (unsigned int)f2bf(lo) | ((unsigned int)f2bf(hi) << 16);
}

// ---------------------------------------------------------------------------
// Kernel 1: QKV projection — 128 rows per block, one LDS W-staging (R11:
// neutral vs 512-block variant at HALF the block count -> proj is HBM/
// latency-bound, not staging-bound; frozen).
// grid 256: jh=bid&1 (column half), rb=bid>>1 covers 128 rows.
// ---------------------------------------------------------------------------
__global__ __launch_bounds__(256, 2) void proj_kernel(
    const float* __restrict__ emb,
    const float* __restrict__ Wq, const float* __restrict__ Wk, const float* __restrict__ Wv,
    const float* __restrict__ bq, const float* __restrict__ bk, const float* __restrict__ bv,
    unsigned short* __restrict__ qg, unsigned short* __restrict__ kg,
    unsigned short* __restrict__ v_t)
{
    const int bid  = blockIdx.x;
    const int tid  = threadIdx.x;
    const int wave = tid >> 6, lane = tid & 63, quad = lane >> 4, l15 = lane & 15;
    const int jh   = bid & 1;
    const int rb   = bid >> 1;
    const int row0 = rb * 128;            // flat row in [0, B*T)

    __shared__ unsigned short Wl[96 * WLS];   // W^T staging [lr][e]
    __shared__ unsigned short vtr[64 * PLS];  // V tile transpose (per half)

    // ---- stage the 96 needed W columns, transposed+bf16: Wl[lr][e] ----
    {   // segment A: jh0: Wq cols 0..63 -> lr 0..63; jh1: Wv 0..63 -> lr 32..95
        const float* __restrict__ srcA = jh ? Wv : Wq;
        const int lrbA = jh ? 32 : 0;
#pragma unroll
        for (int it = 0; it < 16; it++) {
            const int idx = it * 256 + tid;
            const int col = idx & 63;
            const int e0  = (idx >> 6) * 4;
            const float w0 = srcA[(size_t)(e0 + 0) * An + col];
            const float w1 = srcA[(size_t)(e0 + 1) * An + col];
            const float w2 = srcA[(size_t)(e0 + 2) * An + col];
            const float w3 = srcA[(size_t)(e0 + 3) * An + col];
            *(short4v*)&Wl[(lrbA + col) * WLS + e0] =
                (short4v){(short)f2bf(w0), (short)f2bf(w1), (short)f2bf(w2), (short)f2bf(w3)};
        }
        // segment B: Wk (jh0: cols 0..31 -> lr 64..95; jh1: cols 32..63 -> lr 0..31)
        const int coloff = jh ? 32 : 0;
        const int lrbB   = jh ? 0 : 64;
#pragma unroll
        for (int it = 0; it < 8; it++) {
            const int idx = it * 256 + tid;
            const int col = idx & 31;
            const int e0  = (idx >> 5) * 4;
            const float w0 = Wk[(size_t)(e0 + 0) * An + coloff + col];
            const float w1 = Wk[(size_t)(e0 + 1) * An + coloff + col];
            const float w2 = Wk[(size_t)(e0 + 2) * An + coloff + col];
            const float w3 = Wk[(size_t)(e0 + 3) * An + coloff + col];
            *(short4v*)&Wl[(lrbB + col) * WLS + e0] =
                (short4v){(short)f2bf(w0), (short)f2bf(w1), (short)f2bf(w2), (short)f2bf(w3)};
        }
    }
    __syncthreads();

#pragma unroll 1
    for (int h = 0; h < 2; h++) {
        const int row0h = row0 + h * 64;
        const int b     = row0h >> 12;
        const int trow0 = row0h & 4095;

        // ---- A-fragments: emb rows fp32 -> bf16, A[m=l15][k=quad*8+j] ----
        short8 A[8];
        {
            const float* erow = emb + (size_t)(row0h + wave * 16 + l15) * En;
#pragma unroll
            for (int c = 0; c < 8; c++) {
                const float* pp = erow + c * 32 + quad * 8;
                float4 f0 = *(const float4*)pp;
                float4 f1 = *(const float4*)(pp + 4);
                A[c] = (short8){(short)f2bf(f0.x), (short)f2bf(f0.y), (short)f2bf(f0.z), (short)f2bf(f0.w),
                                (short)f2bf(f1.x), (short)f2bf(f1.y), (short)f2bf(f1.z), (short)f2bf(f1.w)};
            }
        }

        f32x4 acc[6];
#pragma unroll
        for (int x = 0; x < 6; x++) acc[x] = (f32x4){0.f, 0.f, 0.f, 0.f};

#pragma unroll
        for (int x = 0; x < 6; x++) {
            const unsigned short* wrow = &Wl[(x * 16 + l15) * WLS];
#pragma unroll
            for (int c = 0; c < 8; c++)
                acc[x] = mfma16(A[c], *(const short8*)(wrow + c * 32 + quad * 8), acc[x]);
        }

        const float QS = 0.125f * 1.4426950408889634f;   // 1/sqrt(A) * log2(e)
#pragma unroll
        for (int x = 0; x < 6; x++) {
            const int nt = jh * 6 + x;
            const int m  = nt >> 2;
            const int al = (nt & 3) * 16 + l15;
            const float bsv = ((m == 0) ? bq : (m == 1) ? bk : bv)[al];
#pragma unroll
            for (int rg = 0; rg < 4; rg++) {
                const int row_l = wave * 16 + quad * 4 + rg;   // C/D: row=quad*4+reg, col=l15
                const float val = acc[x][rg] + bsv;
                if (m == 0)      qg[(size_t)(row0h + row_l) * An + al] = f2bf(val * QS);
                else if (m == 1) kg[(size_t)(row0h + row_l) * An + al] = f2bf(val);
                else             vtr[al * PLS + row_l] = f2bf(val);
            }
        }
        if (jh == 1) {
            __syncthreads();
            const int a  = tid >> 2;
            const int tg = (tid & 3) * 16;
            unsigned short* dst = v_t + (size_t)(b * 64 + a) * Tn + trow0 + tg;
            *(short8*)dst       = *(const short8*)&vtr[a * PLS + tg];
            *(short8*)(dst + 8) = *(const short8*)&vtr[a * PLS + tg + 8];
            __syncthreads();   // protect vtr before next half overwrites
        }
    }
}

// ---------------------------------------------------------------------------
// Kernel 2: flash attention — DE-PAIRED: one block per (b, qt, sb) instead of
// a sequential (p, 63-p) pair per block.  Same total work and same total
// fixed cost (1024 blocks x 1 phase vs 512 x 2), but 1024 blocks = 4
// blocks/CU resident (LDS 37.9KBx4=151KB<160; VGPR 128 -> 16 waves/CU) —
// double the wave parallelism for the latency-bound inner chain.  Imbalance
// (work ∝ qt+1) smoothed by 4x oversubscription; longest block ~4 kv-iters.
// Loop body / softmax / in-block merge byte-identical to R10 ledger-best.
// grid (64*S4, 4).  ub: qt = ub>>(lgS-2), sb = ub&(S4-1), s = 4*sb+wave.
// ---------------------------------------------------------------------------
__global__ __launch_bounds__(256, 2) void flash_kernel(
    const unsigned short* __restrict__ qg, const unsigned short* __restrict__ kg,
    const unsigned short* __restrict__ v_t,
    unsigned short* __restrict__ Opart, float* __restrict__ Lp,
    int S, int lgS)
{
    const int b    = blockIdx.y;
    const int tid  = threadIdx.x;
    const int wave = tid >> 6, lane = tid & 63, quad = lane >> 4, l15 = lane & 15;
    const int ub   = blockIdx.x;
    const int S4   = S >> 2;
    const int qt   = ub >> (lgS - 2);     // 0..63
    const int sb   = ub & (S4 - 1);
    const int s    = sb * 4 + wave;

    __shared__ unsigned short lds[4 * 64 * PLS];   // per-wave 64-row P/O slice
    __shared__ float lW[4][64];
    unsigned short* tw = lds + wave * (64 * PLS);

    const unsigned short* kb0 = kg  + ((size_t)b << 12) * An;
    const unsigned short* vb0 = v_t + (size_t)b * An * Tn;

    const int qrow0 = qt * 64;
    const int tmax  = qt;

    // Q B-fragments: B[k=a][n=qrow], group g = qrows 16g..16g+15
    short8 qB[4][2];
    {
        const unsigned short* qb = qg + (((size_t)b << 12) + qrow0) * An;
#pragma unroll
        for (int g = 0; g < 4; g++)
#pragma unroll
            for (int c = 0; c < 2; c++)
                qB[g][c] = *(const short8*)(qb + (size_t)(16 * g + l15) * An + c * 32 + quad * 8);
    }

    float lacc[4] = {0.f, 0.f, 0.f, 0.f};
    f32x4 O[4][4];
#pragma unroll
    for (int nt = 0; nt < 4; nt++)
#pragma unroll
        for (int g = 0; g < 4; g++) O[nt][g] = (f32x4){0.f, 0.f, 0.f, 0.f};

    for (int t = s; t <= tmax; t += S) {
        // K fragments for t (issued first; QK waits only on these)
        short8 KA[4][2];
        {
            const unsigned short* kb = kb0 + (size_t)t * (64 * An);
#pragma unroll
            for (int nt = 0; nt < 4; nt++)
#pragma unroll
                for (int c = 0; c < 2; c++)
                    KA[nt][c] = *(const short8*)(kb + (nt * 16 + l15) * An + c * 32 + quad * 8);
        }
        // V^T fragments for t (consumed at end -> latency hidden)
        short8 VA[4][2];
        {
            const unsigned short* vb = vb0 + (size_t)t * 64;
#pragma unroll
            for (int nt = 0; nt < 4; nt++)
#pragma unroll
                for (int c = 0; c < 2; c++)
                    VA[nt][c] = *(const short8*)(vb + (size_t)(nt * 16 + l15) * Tn + c * 32 + quad * 8);
        }

        const bool diag = (t == tmax);

        // per q-column group: S^T slab, exp2 (fixed zero), P->LDS, PV
#pragma unroll
        for (int g = 0; g < 4; g++) {
            // S^T[kv=16nt+quad*4+rg][qrow=16g+l15] : 8 MFMA
            f32x4 St[4];
            __builtin_amdgcn_s_setprio(1);
#pragma unroll
            for (int nt = 0; nt < 4; nt++) {
                f32x4 a0 = (f32x4){0.f, 0.f, 0.f, 0.f};
                a0 = mfma16(KA[nt][0], qB[g][0], a0);
                a0 = mfma16(KA[nt][1], qB[g][1], a0);
                St[nt] = a0;
            }
            __builtin_amdgcn_s_setprio(0);
            if (diag) {
                const int qr = 16 * g + l15;        // local q-row
                const int kvb = quad * 4;
#pragma unroll
                for (int nt = 0; nt < 4; nt++)
#pragma unroll
                    for (int rg = 0; rg < 4; rg++)
                        if (nt * 16 + kvb + rg > qr) St[nt][rg] = -__builtin_inff();
            }
            // fixed-zero-point softmax numerator: p = 2^s (no max)
            float rs = 0.f;
#pragma unroll
            for (int nt = 0; nt < 4; nt++) {
                const float p0 = exp2f(St[nt][0]);
                const float p1 = exp2f(St[nt][1]);
                const float p2 = exp2f(St[nt][2]);
                const float p3 = exp2f(St[nt][3]);
                rs += (p0 + p1) + (p2 + p3);
                const unsigned int d0 = packbf2(p0, p1);
                const unsigned int d1 = packbf2(p2, p3);
                *(short4v*)&tw[(16 * g + l15) * PLS + 16 * nt + quad * 4] =
                    __builtin_bit_cast(short4v, (uint2v){d0, d1});
            }
            lacc[g] += rs;
            // P^T B-fragments from LDS (same-wave RAW); O^T += V^T P^T
#pragma unroll
            for (int c = 0; c < 2; c++) {
                const short8 pb = *(const short8*)&tw[(16 * g + l15) * PLS + c * 32 + quad * 8];
                __builtin_amdgcn_s_setprio(1);
#pragma unroll
                for (int nt = 0; nt < 4; nt++)
                    O[nt][g] = mfma16(VA[nt][c], pb, O[nt][g]);
                __builtin_amdgcn_s_setprio(0);
            }
        }
    }

    // ---- per-wave epilogue: O^T -> tw (bf16), l row-sums -> lW ----
#pragma unroll
    for (int nt = 0; nt < 4; nt++)
#pragma unroll
        for (int g = 0; g < 4; g++) {
            const unsigned int d0 = packbf2(O[nt][g][0], O[nt][g][1]);
            const unsigned int d1 = packbf2(O[nt][g][2], O[nt][g][3]);
            *(short4v*)&tw[(16 * g + l15) * PLS + 16 * nt + quad * 4] =
                __builtin_bit_cast(short4v, (uint2v){d0, d1});
        }
#pragma unroll
    for (int g = 0; g < 4; g++) {
        lacc[g] += __shfl_xor(lacc[g], 16);
        lacc[g] += __shfl_xor(lacc[g], 32);
    }
    if (quad == 0) {
#pragma unroll
        for (int g = 0; g < 4; g++) lW[wave][16 * g + l15] = lacc[g];
    }
    __syncthreads();

    // ---- in-block merge of the 4 stripe partials (plain sums) ----
    {
        const int row = tid >> 2;
        const int a16 = (tid & 3) * 16;
        float acc[16];
#pragma unroll
        for (int x = 0; x < 16; x++) acc[x] = 0.f;
        float lsum = 0.f;
#pragma unroll
        for (int w = 0; w < 4; w++) {
            const unsigned short* src = lds + w * (64 * PLS) + row * PLS + a16;
            const short8 o0 = *(const short8*)src;
            const short8 o1 = *(const short8*)(src + 8);
#pragma unroll
            for (int x = 0; x < 8; x++) {
                acc[x]     += bf2f((unsigned short)o0[x]);
                acc[8 + x] += bf2f((unsigned short)o1[x]);
            }
            lsum += lW[w][row];
        }
        const size_t unit = (size_t)(b * 64 + qt) * (size_t)S4 + sb;
        unsigned short* ob = Opart + unit * 4096 + row * 64 + a16;
        short8 r0, r1;
#pragma unroll
        for (int x = 0; x < 8; x++) {
            r0[x] = (short)f2bf(acc[x]);
            r1[x] = (short)f2bf(acc[8 + x]);
        }
        *(short8*)ob       = r0;
        *(short8*)(ob + 8) = r1;
        if ((tid & 3) == 0) Lp[unit * 64 + row] = lsum;
    }
}

// ---------------------------------------------------------------------------
// Kernel 3: merge the S4 stripe-block partials -> out fp32 (frozen).
// grid (256, 4) = 1024 blocks; block covers 16 rows; loads overlap across sb.
// ---------------------------------------------------------------------------
__global__ __launch_bounds__(256) void merge_kernel(
    const unsigned short* __restrict__ Opart, const float* __restrict__ Lp,
    float* __restrict__ out, int S4)
{
    const int bx = blockIdx.x, b = blockIdx.y;
    const int qt = bx >> 2, qq = bx & 3;
    const int tid = threadIdx.x;
    const int row = qq * 16 + (tid >> 4);   // 0..63 within q-tile
    const int a4  = (tid & 15) * 4;
    const size_t ub = (size_t)(b * 64 + qt) * (size_t)S4;

    float acc[4] = {0.f, 0.f, 0.f, 0.f};
    float lsum = 0.f;
    for (int sbi = 0; sbi < S4; sbi++) {
        const short4v o = *(const short4v*)&Opart[(ub + sbi) * 4096 + row * 64 + a4];
        acc[0] += bf2f((unsigned short)o[0]);
        acc[1] += bf2f((unsigned short)o[1]);
        acc[2] += bf2f((unsigned short)o[2]);
        acc[3] += bf2f((unsigned short)o[3]);
        lsum += Lp[(ub + sbi) * 64 + row];
    }
    const float inv = 1.f / lsum;
    float* o = out + (((size_t)b << 12) + qt * 64 + row) * An + a4;
    float4 r = {acc[0] * inv, acc[1] * inv, acc[2] * inv, acc[3] * inv};
    *(float4*)o = r;
}

// ---------------------------------------------------------------------------
extern "C" void kernel_launch(void* const* d_in, const int* in_sizes, int n_in,
                              void* d_out, int out_size, void* d_ws, size_t ws_size,
                              hipStream_t stream) {
    const float* emb = (const float*)d_in[0];
    const float* Wk  = (const float*)d_in[1];
    const float* bk  = (const float*)d_in[2];
    const float* Wq  = (const float*)d_in[3];
    const float* bq  = (const float*)d_in[4];
    const float* Wv  = (const float*)d_in[5];
    const float* bv  = (const float*)d_in[6];
    float* out = (float*)d_out;

    char* ws = (char*)d_ws;
    const size_t MB = 1024 * 1024;

    // stripe count 16: S4=4 stripes/block, 64*S4=256 qt-blocks per batch
    int S = 8, lgS = 3;
    if (7 * MB + (size_t)1024 * 8192 <= ws_size) { S = 16; lgS = 4; }
    const int S4 = S >> 2;

    unsigned short* q     = (unsigned short*)(ws);                  // 2 MB
    unsigned short* k     = (unsigned short*)(ws + 2 * MB);         // 2 MB
    unsigned short* v_t   = (unsigned short*)(ws + 4 * MB);         // 2 MB
    float*          Lp    = (float*)(ws + 6 * MB);                  // <=256 KB
    unsigned short* Opart = (unsigned short*)(ws + 7 * MB);         // 256*S4*8 KB

    proj_kernel<<<256, 256, 0, stream>>>(emb, Wq, Wk, Wv, bq, bk, bv, q, k, v_t);
    flash_kernel<<<dim3(64 * S4, 4), 256, 0, stream>>>(q, k, v_t, Opart, Lp, S, lgS);
    merge_kernel<<<dim3(256, 4), 256, 0, stream>>>(Opart, Lp, out, S4);
}

// Round 13
// 122.770 us; speedup vs baseline: 1.0046x; 1.0046x over previous
//
#include <hip/hip_runtime.h>
#include <math.h>

#define Bn 4
#define Tn 4096
#define En 256
#define An 64
#define PLS 72    // P/O LDS row stride in shorts (144 B, 16B-aligned)
#define WLS 264   // W LDS row stride in shorts (528 B, 16B-aligned)

typedef __attribute__((ext_vector_type(8))) short short8;
typedef __attribute__((ext_vector_type(8))) __bf16 bf16x8;
typedef __attribute__((ext_vector_type(4))) float f32x4;
typedef __attribute__((ext_vector_type(4))) short short4v;
typedef __attribute__((ext_vector_type(2))) unsigned int uint2v;

__device__ __forceinline__ f32x4 mfma16(short8 a, short8 b, f32x4 c) {
    return __builtin_amdgcn_mfma_f32_16x16x32_bf16(
        __builtin_bit_cast(bf16x8, a), __builtin_bit_cast(bf16x8, b), c, 0, 0, 0);
}
__device__ __forceinline__ unsigned short f2bf(float x) {   // native RNE cvt
    return __builtin_bit_cast(unsigned short, (__bf16)x);
}
__device__ __forceinline__ float bf2f(unsigned short h) {
    return __builtin_bit_cast(float, (unsigned int)h << 16);
}
__device__ __forceinline__ unsigned int packbf2(float lo, float hi) {
    return (unsigned int)f2bf(lo) | ((unsigned int)f2bf(hi) << 16);
}

// ---------------------------------------------------------------------------
// Kernel 1: QKV projection — 128 rows per block, one LDS W-staging (R11:
// equal speed to 512-block variant at half the staging work; frozen).
// grid 256: jh=bid&1 (column half), rb=bid>>1 covers 128 rows.
// ---------------------------------------------------------------------------
__global__ __launch_bounds__(256, 2) void proj_kernel(
    const float* __restrict__ emb,
    const float* __restrict__ Wq, const float* __restrict__ Wk, const float* __restrict__ Wv,
    const float* __restrict__ bq, const float* __restrict__ bk, const float* __restrict__ bv,
    unsigned short* __restrict__ qg, unsigned short* __restrict__ kg,
    unsigned short* __restrict__ v_t)
{
    const int bid  = blockIdx.x;
    const int tid  = threadIdx.x;
    const int wave = tid >> 6, lane = tid & 63, quad = lane >> 4, l15 = lane & 15;
    const int jh   = bid & 1;
    const int rb   = bid >> 1;
    const int row0 = rb * 128;            // flat row in [0, B*T)

    __shared__ unsigned short Wl[96 * WLS];   // W^T staging [lr][e]
    __shared__ unsigned short vtr[64 * PLS];  // V tile transpose (per half)

    // ---- stage the 96 needed W columns, transposed+bf16: Wl[lr][e] ----
    {   // segment A: jh0: Wq cols 0..63 -> lr 0..63; jh1: Wv 0..63 -> lr 32..95
        const float* __restrict__ srcA = jh ? Wv : Wq;
        const int lrbA = jh ? 32 : 0;
#pragma unroll
        for (int it = 0; it < 16; it++) {
            const int idx = it * 256 + tid;
            const int col = idx & 63;
            const int e0  = (idx >> 6) * 4;
            const float w0 = srcA[(size_t)(e0 + 0) * An + col];
            const float w1 = srcA[(size_t)(e0 + 1) * An + col];
            const float w2 = srcA[(size_t)(e0 + 2) * An + col];
            const float w3 = srcA[(size_t)(e0 + 3) * An + col];
            *(short4v*)&Wl[(lrbA + col) * WLS + e0] =
                (short4v){(short)f2bf(w0), (short)f2bf(w1), (short)f2bf(w2), (short)f2bf(w3)};
        }
        // segment B: Wk (jh0: cols 0..31 -> lr 64..95; jh1: cols 32..63 -> lr 0..31)
        const int coloff = jh ? 32 : 0;
        const int lrbB   = jh ? 0 : 64;
#pragma unroll
        for (int it = 0; it < 8; it++) {
            const int idx = it * 256 + tid;
            const int col = idx & 31;
            const int e0  = (idx >> 5) * 4;
            const float w0 = Wk[(size_t)(e0 + 0) * An + coloff + col];
            const float w1 = Wk[(size_t)(e0 + 1) * An + coloff + col];
            const float w2 = Wk[(size_t)(e0 + 2) * An + coloff + col];
            const float w3 = Wk[(size_t)(e0 + 3) * An + coloff + col];
            *(short4v*)&Wl[(lrbB + col) * WLS + e0] =
                (short4v){(short)f2bf(w0), (short)f2bf(w1), (short)f2bf(w2), (short)f2bf(w3)};
        }
    }
    __syncthreads();

#pragma unroll 1
    for (int h = 0; h < 2; h++) {
        const int row0h = row0 + h * 64;
        const int b     = row0h >> 12;
        const int trow0 = row0h & 4095;

        // ---- A-fragments: emb rows fp32 -> bf16, A[m=l15][k=quad*8+j] ----
        short8 A[8];
        {
            const float* erow = emb + (size_t)(row0h + wave * 16 + l15) * En;
#pragma unroll
            for (int c = 0; c < 8; c++) {
                const float* pp = erow + c * 32 + quad * 8;
                float4 f0 = *(const float4*)pp;
                float4 f1 = *(const float4*)(pp + 4);
                A[c] = (short8){(short)f2bf(f0.x), (short)f2bf(f0.y), (short)f2bf(f0.z), (short)f2bf(f0.w),
                                (short)f2bf(f1.x), (short)f2bf(f1.y), (short)f2bf(f1.z), (short)f2bf(f1.w)};
            }
        }

        f32x4 acc[6];
#pragma unroll
        for (int x = 0; x < 6; x++) acc[x] = (f32x4){0.f, 0.f, 0.f, 0.f};

#pragma unroll
        for (int x = 0; x < 6; x++) {
            const unsigned short* wrow = &Wl[(x * 16 + l15) * WLS];
#pragma unroll
            for (int c = 0; c < 8; c++)
                acc[x] = mfma16(A[c], *(const short8*)(wrow + c * 32 + quad * 8), acc[x]);
        }

        const float QS = 0.125f * 1.4426950408889634f;   // 1/sqrt(A) * log2(e)
#pragma unroll
        for (int x = 0; x < 6; x++) {
            const int nt = jh * 6 + x;
            const int m  = nt >> 2;
            const int al = (nt & 3) * 16 + l15;
            const float bsv = ((m == 0) ? bq : (m == 1) ? bk : bv)[al];
#pragma unroll
            for (int rg = 0; rg < 4; rg++) {
                const int row_l = wave * 16 + quad * 4 + rg;   // C/D: row=quad*4+reg, col=l15
                const float val = acc[x][rg] + bsv;
                if (m == 0)      qg[(size_t)(row0h + row_l) * An + al] = f2bf(val * QS);
                else if (m == 1) kg[(size_t)(row0h + row_l) * An + al] = f2bf(val);
                else             vtr[al * PLS + row_l] = f2bf(val);
            }
        }
        if (jh == 1) {
            __syncthreads();
            const int a  = tid >> 2;
            const int tg = (tid & 3) * 16;
            unsigned short* dst = v_t + (size_t)(b * 64 + a) * Tn + trow0 + tg;
            *(short8*)dst       = *(const short8*)&vtr[a * PLS + tg];
            *(short8*)(dst + 8) = *(const short8*)&vtr[a * PLS + tg + 8];
            __syncthreads();   // protect vtr before next half overwrites
        }
    }
}

// ---------------------------------------------------------------------------
// Kernel 2: flash attention — R10 PAIRED BODY VERBATIM (frozen; measured
// optimum of 6 variants).  Gamble ledger on this body (all A/B'd):
//   paired 2-phase = best  <  de-paired 4blk/CU (+3.3us, R12)
//   (256,2)/128reg = best  <  (256,1)/168reg no-spill (+10us, R7)
//   VA at loop top = best  <  VA sunk in PV (+18us, R6)
//   no tw swizzle  = best  <  XOR swizzle (+31us, R8)
//   KN removed     = best  (−9.7us vs KN prefetch, R10)
//   S=16           = best  (S=32 wash/worse, R2)
// grid (8*S, 4).  ub: p = ub>>(lgS-2), sb = ub&(S4-1), s = 4*sb+wave.
// ---------------------------------------------------------------------------
__global__ __launch_bounds__(256, 2) void flash_kernel(
    const unsigned short* __restrict__ qg, const unsigned short* __restrict__ kg,
    const unsigned short* __restrict__ v_t,
    unsigned short* __restrict__ Opart, float* __restrict__ Lp,
    int S, int lgS)
{
    const int b    = blockIdx.y;
    const int tid  = threadIdx.x;
    const int wave = tid >> 6, lane = tid & 63, quad = lane >> 4, l15 = lane & 15;
    const int ub   = blockIdx.x;
    const int S4   = S >> 2;
    const int p    = ub >> (lgS - 2);     // 0..31
    const int sb   = ub & (S4 - 1);
    const int s    = sb * 4 + wave;

    __shared__ unsigned short lds[4 * 64 * PLS];   // per-wave 64-row P/O slice
    __shared__ float lW[4][64];
    unsigned short* tw = lds + wave * (64 * PLS);

    const unsigned short* kb0 = kg  + ((size_t)b << 12) * An;
    const unsigned short* vb0 = v_t + (size_t)b * An * Tn;

#pragma unroll 1
    for (int tile = 0; tile < 2; tile++) {
        const int qt    = tile ? (63 - p) : p;   // 64-row tile index
        const int qrow0 = qt * 64;
        const int tmax  = qt;

        // Q B-fragments: B[k=a][n=qrow], group g = qrows 16g..16g+15
        short8 qB[4][2];
        {
            const unsigned short* qb = qg + (((size_t)b << 12) + qrow0) * An;
#pragma unroll
            for (int g = 0; g < 4; g++)
#pragma unroll
                for (int c = 0; c < 2; c++)
                    qB[g][c] = *(const short8*)(qb + (size_t)(16 * g + l15) * An + c * 32 + quad * 8);
        }

        float lacc[4] = {0.f, 0.f, 0.f, 0.f};
        f32x4 O[4][4];
#pragma unroll
        for (int nt = 0; nt < 4; nt++)
#pragma unroll
            for (int g = 0; g < 4; g++) O[nt][g] = (f32x4){0.f, 0.f, 0.f, 0.f};

        for (int t = s; t <= tmax; t += S) {
            // K fragments for t (issued first; QK waits only on these)
            short8 KA[4][2];
            {
                const unsigned short* kb = kb0 + (size_t)t * (64 * An);
#pragma unroll
                for (int nt = 0; nt < 4; nt++)
#pragma unroll
                    for (int c = 0; c < 2; c++)
                        KA[nt][c] = *(const short8*)(kb + (nt * 16 + l15) * An + c * 32 + quad * 8);
            }
            // V^T fragments for t (consumed at end -> latency hidden)
            short8 VA[4][2];
            {
                const unsigned short* vb = vb0 + (size_t)t * 64;
#pragma unroll
                for (int nt = 0; nt < 4; nt++)
#pragma unroll
                    for (int c = 0; c < 2; c++)
                        VA[nt][c] = *(const short8*)(vb + (size_t)(nt * 16 + l15) * Tn + c * 32 + quad * 8);
            }

            const bool diag = (t == tmax);

            // per q-column group: S^T slab, exp2 (fixed zero), P->LDS, PV
#pragma unroll
            for (int g = 0; g < 4; g++) {
                // S^T[kv=16nt+quad*4+rg][qrow=16g+l15] : 8 MFMA
                f32x4 St[4];
                __builtin_amdgcn_s_setprio(1);
#pragma unroll
                for (int nt = 0; nt < 4; nt++) {
                    f32x4 a0 = (f32x4){0.f, 0.f, 0.f, 0.f};
                    a0 = mfma16(KA[nt][0], qB[g][0], a0);
                    a0 = mfma16(KA[nt][1], qB[g][1], a0);
                    St[nt] = a0;
                }
                __builtin_amdgcn_s_setprio(0);
                if (diag) {
                    const int qr = 16 * g + l15;        // local q-row
                    const int kvb = quad * 4;
#pragma unroll
                    for (int nt = 0; nt < 4; nt++)
#pragma unroll
                        for (int rg = 0; rg < 4; rg++)
                            if (nt * 16 + kvb + rg > qr) St[nt][rg] = -__builtin_inff();
                }
                // fixed-zero-point softmax numerator: p = 2^s (no max)
                float rs = 0.f;
#pragma unroll
                for (int nt = 0; nt < 4; nt++) {
                    const float p0 = exp2f(St[nt][0]);
                    const float p1 = exp2f(St[nt][1]);
                    const float p2 = exp2f(St[nt][2]);
                    const float p3 = exp2f(St[nt][3]);
                    rs += (p0 + p1) + (p2 + p3);
                    const unsigned int d0 = packbf2(p0, p1);
                    const unsigned int d1 = packbf2(p2, p3);
                    *(short4v*)&tw[(16 * g + l15) * PLS + 16 * nt + quad * 4] =
                        __builtin_bit_cast(short4v, (uint2v){d0, d1});
                }
                lacc[g] += rs;
                // P^T B-fragments from LDS (same-wave RAW); O^T += V^T P^T
#pragma unroll
                for (int c = 0; c < 2; c++) {
                    const short8 pb = *(const short8*)&tw[(16 * g + l15) * PLS + c * 32 + quad * 8];
                    __builtin_amdgcn_s_setprio(1);
#pragma unroll
                    for (int nt = 0; nt < 4; nt++)
                        O[nt][g] = mfma16(VA[nt][c], pb, O[nt][g]);
                    __builtin_amdgcn_s_setprio(0);
                }
            }
        }

        // ---- per-wave epilogue: O^T -> tw (bf16), l row-sums -> lW ----
#pragma unroll
        for (int nt = 0; nt < 4; nt++)
#pragma unroll
            for (int g = 0; g < 4; g++) {
                const unsigned int d0 = packbf2(O[nt][g][0], O[nt][g][1]);
                const unsigned int d1 = packbf2(O[nt][g][2], O[nt][g][3]);
                *(short4v*)&tw[(16 * g + l15) * PLS + 16 * nt + quad * 4] =
                    __builtin_bit_cast(short4v, (uint2v){d0, d1});
            }
#pragma unroll
        for (int g = 0; g < 4; g++) {
            lacc[g] += __shfl_xor(lacc[g], 16);
            lacc[g] += __shfl_xor(lacc[g], 32);
        }
        if (quad == 0) {
#pragma unroll
            for (int g = 0; g < 4; g++) lW[wave][16 * g + l15] = lacc[g];
        }
        __syncthreads();

        // ---- in-block merge of the 4 stripe partials (plain sums) ----
        {
            const int row = tid >> 2;
            const int a16 = (tid & 3) * 16;
            float acc[16];
#pragma unroll
            for (int x = 0; x < 16; x++) acc[x] = 0.f;
            float lsum = 0.f;
#pragma unroll
            for (int w = 0; w < 4; w++) {
                const unsigned short* src = lds + w * (64 * PLS) + row * PLS + a16;
                const short8 o0 = *(const short8*)src;
                const short8 o1 = *(const short8*)(src + 8);
#pragma unroll
                for (int x = 0; x < 8; x++) {
                    acc[x]     += bf2f((unsigned short)o0[x]);
                    acc[8 + x] += bf2f((unsigned short)o1[x]);
                }
                lsum += lW[w][row];
            }
            const size_t unit = (size_t)(b * 64 + qt) * (size_t)S4 + sb;
            unsigned short* ob = Opart + unit * 4096 + row * 64 + a16;
            short8 r0, r1;
#pragma unroll
            for (int x = 0; x < 8; x++) {
                r0[x] = (short)f2bf(acc[x]);
                r1[x] = (short)f2bf(acc[8 + x]);
            }
            *(short8*)ob       = r0;
            *(short8*)(ob + 8) = r1;
            if ((tid & 3) == 0) Lp[unit * 64 + row] = lsum;
        }
        __syncthreads();   // protect tw reuse by next tile
    }
}

// ---------------------------------------------------------------------------
// Kernel 3: merge — NEW: 16B loads (short8 per stripe per thread), thread
// covers 8 a-columns.  grid (128, 4) = 512 blocks (2/CU); per-thread work
// x2, instructions/byte halved, still fully coalesced (8 threads = 128B run
// of one row).  Was ~1.5 TB/s effective with 8B loads.
// ---------------------------------------------------------------------------
__global__ __launch_bounds__(256) void merge_kernel(
    const unsigned short* __restrict__ Opart, const float* __restrict__ Lp,
    float* __restrict__ out, int S4)
{
    const int bx = blockIdx.x, b = blockIdx.y;
    const int qt = bx >> 1, half = bx & 1;
    const int tid = threadIdx.x;
    const int row = half * 32 + (tid >> 3);   // 32 rows/block
    const int a8  = (tid & 7) * 8;
    const size_t ub = (size_t)(b * 64 + qt) * (size_t)S4;

    float acc[8];
#pragma unroll
    for (int x = 0; x < 8; x++) acc[x] = 0.f;
    float lsum = 0.f;
    for (int sbi = 0; sbi < S4; sbi++) {
        const short8 o = *(const short8*)&Opart[(ub + sbi) * 4096 + row * 64 + a8];
#pragma unroll
        for (int x = 0; x < 8; x++) acc[x] += bf2f((unsigned short)o[x]);
        lsum += Lp[(ub + sbi) * 64 + row];
    }
    const float inv = 1.f / lsum;
    float* o = out + (((size_t)b << 12) + qt * 64 + row) * An + a8;
    float4 r0 = {acc[0] * inv, acc[1] * inv, acc[2] * inv, acc[3] * inv};
    float4 r1 = {acc[4] * inv, acc[5] * inv, acc[6] * inv, acc[7] * inv};
    *(float4*)o       = r0;
    *(float4*)(o + 4) = r1;
}

// ---------------------------------------------------------------------------
extern "C" void kernel_launch(void* const* d_in, const int* in_sizes, int n_in,
                              void* d_out, int out_size, void* d_ws, size_t ws_size,
                              hipStream_t stream) {
    const float* emb = (const float*)d_in[0];
    const float* Wk  = (const float*)d_in[1];
    const float* bk  = (const float*)d_in[2];
    const float* Wq  = (const float*)d_in[3];
    const float* bq  = (const float*)d_in[4];
    const float* Wv  = (const float*)d_in[5];
    const float* bv  = (const float*)d_in[6];
    float* out = (float*)d_out;

    char* ws = (char*)d_ws;
    const size_t MB = 1024 * 1024;

    // stripe count 16 (512 paired flash blocks): best measured amortization
    int S = 8, lgS = 3;
    if (7 * MB + (size_t)1024 * 8192 <= ws_size) { S = 16; lgS = 4; }
    const int S4 = S >> 2;

    unsigned short* q     = (unsigned short*)(ws);                  // 2 MB
    unsigned short* k     = (unsigned short*)(ws + 2 * MB);         // 2 MB
    unsigned short* v_t   = (unsigned short*)(ws + 4 * MB);         // 2 MB
    float*          Lp    = (float*)(ws + 6 * MB);                  // <=256 KB
    unsigned short* Opart = (unsigned short*)(ws + 7 * MB);         // 256*S4*8 KB

    proj_kernel<<<256, 256, 0, stream>>>(emb, Wq, Wk, Wv, bq, bk, bv, q, k, v_t);
    flash_kernel<<<dim3(8 * S, 4), 256, 0, stream>>>(q, k, v_t, Opart, Lp, S, lgS);
    merge_kernel<<<dim3(128, 4), 256, 0, stream>>>(Opart, Lp, out, S4);
}

// Round 14
// 118.961 us; speedup vs baseline: 1.0368x; 1.0320x over previous
//
#include <hip/hip_runtime.h>
#include <math.h>

#define Bn 4
#define Tn 4096
#define En 256
#define An 64
#define PLS 72    // P/O LDS row stride in shorts (144 B, 16B-aligned)
#define WLS 264   // W LDS row stride in shorts (528 B, 16B-aligned)

typedef __attribute__((ext_vector_type(8))) short short8;
typedef __attribute__((ext_vector_type(8))) __bf16 bf16x8;
typedef __attribute__((ext_vector_type(4))) float f32x4;
typedef __attribute__((ext_vector_type(4))) short short4v;
typedef __attribute__((ext_vector_type(2))) unsigned int uint2v;

__device__ __forceinline__ f32x4 mfma16(short8 a, short8 b, f32x4 c) {
    return __builtin_amdgcn_mfma_f32_16x16x32_bf16(
        __builtin_bit_cast(bf16x8, a), __builtin_bit_cast(bf16x8, b), c, 0, 0, 0);
}
__device__ __forceinline__ unsigned short f2bf(float x) {   // native RNE cvt
    return __builtin_bit_cast(unsigned short, (__bf16)x);
}
__device__ __forceinline__ float bf2f(unsigned short h) {
    return __builtin_bit_cast(float, (unsigned int)h << 16);
}
__device__ __forceinline__ unsigned int packbf2(float lo, float hi) {
    return (unsigned int)f2bf(lo) | ((unsigned int)f2bf(hi) << 16);
}

// ---------------------------------------------------------------------------
// SESSION-BEST CONFIGURATION (measured 120.0us, R10): proj-512 (round-2
// body) + flash-R10 (paired, KN-free, (256,2)) + merge (256,4).  Later
// variants (proj-128 R11, de-pair R12, merge-16B R13) were all within the
// ±1.5us noise band or worse; this triple is the measured optimum.
// ---------------------------------------------------------------------------

// ---------------------------------------------------------------------------
// Kernel 1: QKV projection with in-block W staging.
// grid 512: jh=bid&1 (column half), row-block = bid>>1.
// ---------------------------------------------------------------------------
__global__ __launch_bounds__(256, 2) void proj_kernel(
    const float* __restrict__ emb,
    const float* __restrict__ Wq, const float* __restrict__ Wk, const float* __restrict__ Wv,
    const float* __restrict__ bq, const float* __restrict__ bk, const float* __restrict__ bv,
    unsigned short* __restrict__ qg, unsigned short* __restrict__ kg,
    unsigned short* __restrict__ v_t)
{
    const int bid  = blockIdx.x;
    const int tid  = threadIdx.x;
    const int wave = tid >> 6, lane = tid & 63, quad = lane >> 4, l15 = lane & 15;
    const int jh   = bid & 1;
    const int rb   = bid >> 1;
    const int row0  = rb * 64;            // flat row in [0, B*T)
    const int b     = row0 >> 12;
    const int trow0 = row0 & 4095;

    __shared__ unsigned short Wl[96 * WLS];   // W^T staging [lr][e]
    __shared__ unsigned short vtr[64 * PLS];  // V tile transpose

    // ---- stage the 96 needed W columns, transposed+bf16: Wl[lr][e] ----
    {   // segment A: jh0: Wq cols 0..63 -> lr 0..63; jh1: Wv 0..63 -> lr 32..95
        const float* __restrict__ srcA = jh ? Wv : Wq;
        const int lrbA = jh ? 32 : 0;
#pragma unroll
        for (int it = 0; it < 16; it++) {
            const int idx = it * 256 + tid;
            const int col = idx & 63;
            const int e0  = (idx >> 6) * 4;
            const float w0 = srcA[(size_t)(e0 + 0) * An + col];
            const float w1 = srcA[(size_t)(e0 + 1) * An + col];
            const float w2 = srcA[(size_t)(e0 + 2) * An + col];
            const float w3 = srcA[(size_t)(e0 + 3) * An + col];
            *(short4v*)&Wl[(lrbA + col) * WLS + e0] =
                (short4v){(short)f2bf(w0), (short)f2bf(w1), (short)f2bf(w2), (short)f2bf(w3)};
        }
        // segment B: Wk (jh0: cols 0..31 -> lr 64..95; jh1: cols 32..63 -> lr 0..31)
        const int coloff = jh ? 32 : 0;
        const int lrbB   = jh ? 0 : 64;
#pragma unroll
        for (int it = 0; it < 8; it++) {
            const int idx = it * 256 + tid;
            const int col = idx & 31;
            const int e0  = (idx >> 5) * 4;
            const float w0 = Wk[(size_t)(e0 + 0) * An + coloff + col];
            const float w1 = Wk[(size_t)(e0 + 1) * An + coloff + col];
            const float w2 = Wk[(size_t)(e0 + 2) * An + coloff + col];
            const float w3 = Wk[(size_t)(e0 + 3) * An + coloff + col];
            *(short4v*)&Wl[(lrbB + col) * WLS + e0] =
                (short4v){(short)f2bf(w0), (short)f2bf(w1), (short)f2bf(w2), (short)f2bf(w3)};
        }
    }

    // ---- A-fragments: emb rows fp32 -> bf16, A[m=l15][k=quad*8+j] ----
    short8 A[8];
    {
        const float* erow = emb + (size_t)(row0 + wave * 16 + l15) * En;
#pragma unroll
        for (int c = 0; c < 8; c++) {
            const float* pp = erow + c * 32 + quad * 8;
            float4 f0 = *(const float4*)pp;
            float4 f1 = *(const float4*)(pp + 4);
            A[c] = (short8){(short)f2bf(f0.x), (short)f2bf(f0.y), (short)f2bf(f0.z), (short)f2bf(f0.w),
                            (short)f2bf(f1.x), (short)f2bf(f1.y), (short)f2bf(f1.z), (short)f2bf(f1.w)};
        }
    }
    __syncthreads();

    f32x4 acc[6];
#pragma unroll
    for (int x = 0; x < 6; x++) acc[x] = (f32x4){0.f, 0.f, 0.f, 0.f};

#pragma unroll
    for (int x = 0; x < 6; x++) {
        const unsigned short* wrow = &Wl[(x * 16 + l15) * WLS];
#pragma unroll
        for (int c = 0; c < 8; c++)
            acc[x] = mfma16(A[c], *(const short8*)(wrow + c * 32 + quad * 8), acc[x]);
    }

    const float QS = 0.125f * 1.4426950408889634f;   // 1/sqrt(A) * log2(e)
#pragma unroll
    for (int x = 0; x < 6; x++) {
        const int nt = jh * 6 + x;
        const int m  = nt >> 2;
        const int al = (nt & 3) * 16 + l15;
        const float bsv = ((m == 0) ? bq : (m == 1) ? bk : bv)[al];
#pragma unroll
        for (int rg = 0; rg < 4; rg++) {
            const int row_l = wave * 16 + quad * 4 + rg;   // C/D: row=quad*4+reg, col=l15
            const float val = acc[x][rg] + bsv;
            if (m == 0)      qg[(size_t)(row0 + row_l) * An + al] = f2bf(val * QS);
            else if (m == 1) kg[(size_t)(row0 + row_l) * An + al] = f2bf(val);
            else             vtr[al * PLS + row_l] = f2bf(val);
        }
    }
    if (jh == 1) {
        __syncthreads();
        const int a  = tid >> 2;
        const int tg = (tid & 3) * 16;
        unsigned short* dst = v_t + (size_t)(b * 64 + a) * Tn + trow0 + tg;
        *(short8*)dst       = *(const short8*)&vtr[a * PLS + tg];
        *(short8*)(dst + 8) = *(const short8*)&vtr[a * PLS + tg + 8];
    }
}

// ---------------------------------------------------------------------------
// Kernel 2: flash attention — R10 PAIRED BODY VERBATIM (measured optimum of
// 6 variants).  Gamble ledger on this body (all A/B'd):
//   paired 2-phase = best  <  de-paired 4blk/CU (+3.3us, R12)
//   (256,2)/128reg = best  <  (256,1)/168reg no-spill (+10us, R7)
//   VA at loop top = best  <  VA sunk in PV (+18us, R6)
//   no tw swizzle  = best  <  XOR swizzle (+31us, R8)
//   KN removed     = best  (−9.7us vs KN prefetch, R10)
//   S=16           = best  (S=32 wash/worse, R2)
// grid (8*S, 4).  ub: p = ub>>(lgS-2), sb = ub&(S4-1), s = 4*sb+wave.
// ---------------------------------------------------------------------------
__global__ __launch_bounds__(256, 2) void flash_kernel(
    const unsigned short* __restrict__ qg, const unsigned short* __restrict__ kg,
    const unsigned short* __restrict__ v_t,
    unsigned short* __restrict__ Opart, float* __restrict__ Lp,
    int S, int lgS)
{
    const int b    = blockIdx.y;
    const int tid  = threadIdx.x;
    const int wave = tid >> 6, lane = tid & 63, quad = lane >> 4, l15 = lane & 15;
    const int ub   = blockIdx.x;
    const int S4   = S >> 2;
    const int p    = ub >> (lgS - 2);     // 0..31
    const int sb   = ub & (S4 - 1);
    const int s    = sb * 4 + wave;

    __shared__ unsigned short lds[4 * 64 * PLS];   // per-wave 64-row P/O slice
    __shared__ float lW[4][64];
    unsigned short* tw = lds + wave * (64 * PLS);

    const unsigned short* kb0 = kg  + ((size_t)b << 12) * An;
    const unsigned short* vb0 = v_t + (size_t)b * An * Tn;

#pragma unroll 1
    for (int tile = 0; tile < 2; tile++) {
        const int qt    = tile ? (63 - p) : p;   // 64-row tile index
        const int qrow0 = qt * 64;
        const int tmax  = qt;

        // Q B-fragments: B[k=a][n=qrow], group g = qrows 16g..16g+15
        short8 qB[4][2];
        {
            const unsigned short* qb = qg + (((size_t)b << 12) + qrow0) * An;
#pragma unroll
            for (int g = 0; g < 4; g++)
#pragma unroll
                for (int c = 0; c < 2; c++)
                    qB[g][c] = *(const short8*)(qb + (size_t)(16 * g + l15) * An + c * 32 + quad * 8);
        }

        float lacc[4] = {0.f, 0.f, 0.f, 0.f};
        f32x4 O[4][4];
#pragma unroll
        for (int nt = 0; nt < 4; nt++)
#pragma unroll
            for (int g = 0; g < 4; g++) O[nt][g] = (f32x4){0.f, 0.f, 0.f, 0.f};

        for (int t = s; t <= tmax; t += S) {
            // K fragments for t (issued first; QK waits only on these)
            short8 KA[4][2];
            {
                const unsigned short* kb = kb0 + (size_t)t * (64 * An);
#pragma unroll
                for (int nt = 0; nt < 4; nt++)
#pragma unroll
                    for (int c = 0; c < 2; c++)
                        KA[nt][c] = *(const short8*)(kb + (nt * 16 + l15) * An + c * 32 + quad * 8);
            }
            // V^T fragments for t (consumed at end -> latency hidden)
            short8 VA[4][2];
            {
                const unsigned short* vb = vb0 + (size_t)t * 64;
#pragma unroll
                for (int nt = 0; nt < 4; nt++)
#pragma unroll
                    for (int c = 0; c < 2; c++)
                        VA[nt][c] = *(const short8*)(vb + (size_t)(nt * 16 + l15) * Tn + c * 32 + quad * 8);
            }

            const bool diag = (t == tmax);

            // per q-column group: S^T slab, exp2 (fixed zero), P->LDS, PV
#pragma unroll
            for (int g = 0; g < 4; g++) {
                // S^T[kv=16nt+quad*4+rg][qrow=16g+l15] : 8 MFMA
                f32x4 St[4];
                __builtin_amdgcn_s_setprio(1);
#pragma unroll
                for (int nt = 0; nt < 4; nt++) {
                    f32x4 a0 = (f32x4){0.f, 0.f, 0.f, 0.f};
                    a0 = mfma16(KA[nt][0], qB[g][0], a0);
                    a0 = mfma16(KA[nt][1], qB[g][1], a0);
                    St[nt] = a0;
                }
                __builtin_amdgcn_s_setprio(0);
                if (diag) {
                    const int qr = 16 * g + l15;        // local q-row
                    const int kvb = quad * 4;
#pragma unroll
                    for (int nt = 0; nt < 4; nt++)
#pragma unroll
                        for (int rg = 0; rg < 4; rg++)
                            if (nt * 16 + kvb + rg > qr) St[nt][rg] = -__builtin_inff();
                }
                // fixed-zero-point softmax numerator: p = 2^s (no max)
                float rs = 0.f;
#pragma unroll
                for (int nt = 0; nt < 4; nt++) {
                    const float p0 = exp2f(St[nt][0]);
                    const float p1 = exp2f(St[nt][1]);
                    const float p2 = exp2f(St[nt][2]);
                    const float p3 = exp2f(St[nt][3]);
                    rs += (p0 + p1) + (p2 + p3);
                    const unsigned int d0 = packbf2(p0, p1);
                    const unsigned int d1 = packbf2(p2, p3);
                    *(short4v*)&tw[(16 * g + l15) * PLS + 16 * nt + quad * 4] =
                        __builtin_bit_cast(short4v, (uint2v){d0, d1});
                }
                lacc[g] += rs;
                // P^T B-fragments from LDS (same-wave RAW); O^T += V^T P^T
#pragma unroll
                for (int c = 0; c < 2; c++) {
                    const short8 pb = *(const short8*)&tw[(16 * g + l15) * PLS + c * 32 + quad * 8];
                    __builtin_amdgcn_s_setprio(1);
#pragma unroll
                    for (int nt = 0; nt < 4; nt++)
                        O[nt][g] = mfma16(VA[nt][c], pb, O[nt][g]);
                    __builtin_amdgcn_s_setprio(0);
                }
            }
        }

        // ---- per-wave epilogue: O^T -> tw (bf16), l row-sums -> lW ----
#pragma unroll
        for (int nt = 0; nt < 4; nt++)
#pragma unroll
            for (int g = 0; g < 4; g++) {
                const unsigned int d0 = packbf2(O[nt][g][0], O[nt][g][1]);
                const unsigned int d1 = packbf2(O[nt][g][2], O[nt][g][3]);
                *(short4v*)&tw[(16 * g + l15) * PLS + 16 * nt + quad * 4] =
                    __builtin_bit_cast(short4v, (uint2v){d0, d1});
            }
#pragma unroll
        for (int g = 0; g < 4; g++) {
            lacc[g] += __shfl_xor(lacc[g], 16);
            lacc[g] += __shfl_xor(lacc[g], 32);
        }
        if (quad == 0) {
#pragma unroll
            for (int g = 0; g < 4; g++) lW[wave][16 * g + l15] = lacc[g];
        }
        __syncthreads();

        // ---- in-block merge of the 4 stripe partials (plain sums) ----
        {
            const int row = tid >> 2;
            const int a16 = (tid & 3) * 16;
            float acc[16];
#pragma unroll
            for (int x = 0; x < 16; x++) acc[x] = 0.f;
            float lsum = 0.f;
#pragma unroll
            for (int w = 0; w < 4; w++) {
                const unsigned short* src = lds + w * (64 * PLS) + row * PLS + a16;
                const short8 o0 = *(const short8*)src;
                const short8 o1 = *(const short8*)(src + 8);
#pragma unroll
                for (int x = 0; x < 8; x++) {
                    acc[x]     += bf2f((unsigned short)o0[x]);
                    acc[8 + x] += bf2f((unsigned short)o1[x]);
                }
                lsum += lW[w][row];
            }
            const size_t unit = (size_t)(b * 64 + qt) * (size_t)S4 + sb;
            unsigned short* ob = Opart + unit * 4096 + row * 64 + a16;
            short8 r0, r1;
#pragma unroll
            for (int x = 0; x < 8; x++) {
                r0[x] = (short)f2bf(acc[x]);
                r1[x] = (short)f2bf(acc[8 + x]);
            }
            *(short8*)ob       = r0;
            *(short8*)(ob + 8) = r1;
            if ((tid & 3) == 0) Lp[unit * 64 + row] = lsum;
        }
        __syncthreads();   // protect tw reuse by next tile
    }
}

// ---------------------------------------------------------------------------
// Kernel 3: merge the S4 stripe-block partials -> out fp32.
// grid (256, 4) = 1024 blocks; block covers 16 rows; loads overlap across sb.
// ---------------------------------------------------------------------------
__global__ __launch_bounds__(256) void merge_kernel(
    const unsigned short* __restrict__ Opart, const float* __restrict__ Lp,
    float* __restrict__ out, int S4)
{
    const int bx = blockIdx.x, b = blockIdx.y;
    const int qt = bx >> 2, qq = bx & 3;
    const int tid = threadIdx.x;
    const int row = qq * 16 + (tid >> 4);   // 0..63 within q-tile
    const int a4  = (tid & 15) * 4;
    const size_t ub = (size_t)(b * 64 + qt) * (size_t)S4;

    float acc[4] = {0.f, 0.f, 0.f, 0.f};
    float lsum = 0.f;
    for (int sbi = 0; sbi < S4; sbi++) {
        const short4v o = *(const short4v*)&Opart[(ub + sbi) * 4096 + row * 64 + a4];
        acc[0] += bf2f((unsigned short)o[0]);
        acc[1] += bf2f((unsigned short)o[1]);
        acc[2] += bf2f((unsigned short)o[2]);
        acc[3] += bf2f((unsigned short)o[3]);
        lsum += Lp[(ub + sbi) * 64 + row];
    }
    const float inv = 1.f / lsum;
    float* o = out + (((size_t)b << 12) + qt * 64 + row) * An + a4;
    float4 r = {acc[0] * inv, acc[1] * inv, acc[2] * inv, acc[3] * inv};
    *(float4*)o = r;
}

// ---------------------------------------------------------------------------
extern "C" void kernel_launch(void* const* d_in, const int* in_sizes, int n_in,
                              void* d_out, int out_size, void* d_ws, size_t ws_size,
                              hipStream_t stream) {
    const float* emb = (const float*)d_in[0];
    const float* Wk  = (const float*)d_in[1];
    const float* bk  = (const float*)d_in[2];
    const float* Wq  = (const float*)d_in[3];
    const float* bq  = (const float*)d_in[4];
    const float* Wv  = (const float*)d_in[5];
    const float* bv  = (const float*)d_in[6];
    float* out = (float*)d_out;

    char* ws = (char*)d_ws;
    const size_t MB = 1024 * 1024;

    // stripe count 16 (512 paired flash blocks): best measured amortization
    int S = 8, lgS = 3;
    if (7 * MB + (size_t)1024 * 8192 <= ws_size) { S = 16; lgS = 4; }
    const int S4 = S >> 2;

    unsigned short* q     = (unsigned short*)(ws);                  // 2 MB
    unsigned short* k     = (unsigned short*)(ws + 2 * MB);         // 2 MB
    unsigned short* v_t   = (unsigned short*)(ws + 4 * MB);         // 2 MB
    float*          Lp    = (float*)(ws + 6 * MB);                  // <=256 KB
    unsigned short* Opart = (unsigned short*)(ws + 7 * MB);         // 256*S4*8 KB

    proj_kernel<<<512, 256, 0, stream>>>(emb, Wq, Wk, Wv, bq, bk, bv, q, k, v_t);
    flash_kernel<<<dim3(8 * S, 4), 256, 0, stream>>>(q, k, v_t, Opart, Lp, S, lgS);
    merge_kernel<<<dim3(256, 4), 256, 0, stream>>>(Opart, Lp, out, S4);
}